// Round 1
// baseline (135.477 us; speedup 1.0000x reference)
//
#include <hip/hip_runtime.h>

// Problem constants (match reference).
#define CDIM 4096   // num_class
#define DDIM 512    // dim_label_emb
// mask = (u > 0.2f) ? 1.25f : 0.f ; cum = running product of 1.25f (exact same
// f32 rounding sequence as jnp.cumprod since mask values are exactly {0,1.25f}).

// Kernel 1: w[j] = sum_k co[k,j] * 1.25^(k+1), stopping at first dead row.
// One thread per column. A wave covers 64 adjacent columns -> coalesced row
// reads. Chunked 8-rows-at-a-time so the 8 loads are independent (latency
// hiding); wave exits via ballot when all its columns are dead. Expected
// chunks per wave: ~4-5 (max run over 64 cols ~ 19 rows). Loop bound stays at
// CDIM for correctness in the (p=0.8^k) long-tail case.
__global__ __launch_bounds__(256) void compute_w_kernel(
        const float* __restrict__ co, const float* __restrict__ mu,
        float* __restrict__ w) {
    int j = blockIdx.x * blockDim.x + threadIdx.x;
    if (j >= CDIM) return;
    float acc = 0.f;
    float scale = 1.25f;   // 1.25^(k+1) at row k
    bool alive = true;
    for (int k0 = 0; k0 < CDIM; k0 += 8) {
        float u[8], c[8];
#pragma unroll
        for (int i = 0; i < 8; ++i) {
            size_t off = (size_t)(k0 + i) * CDIM + j;
            u[i] = mu[off];
            c[i] = co[off];
        }
#pragma unroll
        for (int i = 0; i < 8; ++i) {
            if (alive) {
                if (u[i] > 0.2f) {
                    acc += c[i] * scale;
                    scale *= 1.25f;
                } else {
                    alive = false;
                }
            }
        }
        if (__ballot(alive) == 0ULL) break;
    }
    w[j] = acc;
}

// Kernel 2: per-row fused copy + dot.
// Block d reads row d of label_emb (float4, coalesced), writes it to out
// (output 0), and accumulates dot(row, w) -> out[D*C + d] (output 1).
__global__ __launch_bounds__(256) void dot_copy_kernel(
        const float* __restrict__ emb, const float* __restrict__ w,
        float* __restrict__ out) {
    int d = blockIdx.x;
    const float4* row  = (const float4*)(emb + (size_t)d * CDIM);
    float4*       orow = (float4*)(out + (size_t)d * CDIM);
    const float4* w4   = (const float4*)w;
    float acc = 0.f;
#pragma unroll
    for (int it = 0; it < (CDIM / 4) / 256; ++it) {
        int i = it * 256 + threadIdx.x;
        float4 v  = row[i];
        float4 ww = w4[i];
        orow[i] = v;                       // output 0: pass-through copy
        acc += v.x * ww.x + v.y * ww.y + v.z * ww.z + v.w * ww.w;
    }
    // wave64 shuffle reduce
#pragma unroll
    for (int off = 32; off > 0; off >>= 1) acc += __shfl_down(acc, off, 64);
    __shared__ float part[4];
    int lane = threadIdx.x & 63, wv = threadIdx.x >> 6;
    if (lane == 0) part[wv] = acc;
    __syncthreads();
    if (threadIdx.x == 0)
        out[(size_t)DDIM * CDIM + d] = part[0] + part[1] + part[2] + part[3];
}

extern "C" void kernel_launch(void* const* d_in, const int* in_sizes, int n_in,
                              void* d_out, int out_size, void* d_ws, size_t ws_size,
                              hipStream_t stream) {
    const float* label_emb = (const float*)d_in[0];   // (D, C)
    const float* co        = (const float*)d_in[1];   // (C, C)
    const float* mu        = (const float*)d_in[2];   // (C, C)
    float* out = (float*)d_out;                       // [D*C copy | D dim_emb]
    float* w   = (float*)d_ws;                        // C floats scratch

    compute_w_kernel<<<CDIM / 256, 256, 0, stream>>>(co, mu, w);
    dot_copy_kernel<<<DDIM, 256, 0, stream>>>(label_emb, w, out);
}